// Round 12
// baseline (152.798 us; speedup 1.0000x reference)
//
#include <hip/hip_runtime.h>
#include <stdint.h>

// FactorLayer: B=4096, D=4096, T=16, float32.
// X = znorm(inputs); Y = X@W_static; Z = X@W; sequential deflation collapses
// to 17-dim recurrences on the Gram of [Y|Z|1]; Out = Z - [Y|1]@Wmat.
// Structure (R12): 3 launches. kA: stats partials + zero gram/counter.
// kB: pure GEMM R = (in.diag(inv)) @ [Wstat|W], raw weights s_load'ed via
// wave-uniform jq. kEF: kC merged into kE -- each of 64 blocks reduces its
// own 64 rows from ypart into LDS, contributes gram atomics, then crosses a
// device-atomic arrival barrier (64 blocks always co-resident; cooperative
// launch is broken in this harness per R3) and runs the centered-Gram solve
// + epilogue. Gram re-read uses agent-scope atomic loads (XCD L2 coherence).
// Journal: R7: weight ptr off raw t>>7 kills s_load (use readfirstlane).
// Fixed harness cost ~105-110us (ws poison fill 41us + input restore ~21us
// + gaps); controllable kernel floor ~26us of traffic.

#define BB 4096
#define DD 4096
#define EPSF 1e-6f

// ws layout (float indices)
#define O_PART    0u          // [16 rowgroups][8192]: colsum(0..4095), colsq(4096..8191)
#define O_GRAMM   131072u     // 8 copies x 1120 (33x33, upper-tri used)
#define O_CNT     140032u     // arrival counter (1 word, zeroed by kA)
#define O_YPART   271360u     // [32 dgroups][4096][32] (16B-aligned)

__device__ __forceinline__ int gidx(int a, int b) {   // upper-tri gram index
    int lo = a < b ? a : b, hi = a < b ? b : a;
    return lo * 33 + hi;
}
__device__ __forceinline__ float gload(const float* p) {  // agent-scope load
    return __hip_atomic_load(p, __ATOMIC_RELAXED, __HIP_MEMORY_SCOPE_AGENT);
}

// ============ kA: stats partials (16 rowgroups) + zero gram/counter =========
// 512 blocks = 32 colgroups(128 cols) x 16 rowgroups(256 rows).
__global__ __launch_bounds__(256, 2)
void kA(const float* __restrict__ in, float* __restrict__ ws) {
    __shared__ float rs[8 * 132], rq[8 * 132];        // pad 132: no 8-way bank hits
    int b = blockIdx.x, t = threadIdx.x;
    int idx = b * 256 + t;
    if (idx < 8961) ws[O_GRAMM + idx] = 0.f;          // 8 gram copies + counter
    int cg = b & 31, rg = b >> 5;
    int dbase = cg * 128, r0 = rg * 256;
    int chunk = t & 31, rr = t >> 5;
    int c0 = dbase + chunk * 4;
    float s0=0.f,s1=0.f,s2=0.f,s3=0.f,q0=0.f,q1=0.f,q2=0.f,q3=0.f;
    #pragma unroll 4
    for (int i = 0; i < 32; ++i) {
        int r = r0 + i * 8 + rr;
        float4 u = *(const float4*)&in[(size_t)r * DD + c0];
        s0 += u.x; q0 += u.x*u.x;  s1 += u.y; q1 += u.y*u.y;
        s2 += u.z; q2 += u.z*u.z;  s3 += u.w; q3 += u.w*u.w;
    }
    int lb = rr * 132 + chunk * 4;
    rs[lb+0]=s0; rs[lb+1]=s1; rs[lb+2]=s2; rs[lb+3]=s3;
    rq[lb+0]=q0; rq[lb+1]=q1; rq[lb+2]=q2; rq[lb+3]=q3;
    __syncthreads();
    float* part = ws + O_PART + (size_t)rg * 8192;
    if (t < 128) {
        float a = 0.f;
        #pragma unroll
        for (int r2 = 0; r2 < 8; ++r2) a += rs[r2 * 132 + t];
        part[dbase + t] = a;
    } else {
        int ci = t - 128;
        float a = 0.f;
        #pragma unroll
        for (int r2 = 0; r2 < 8; ++r2) a += rq[r2 * 132 + ci];
        part[4096 + dbase + ci] = a;
    }
}

// ============ kB: inv-prologue + pure GEMM R = (in.inv) @ Wcat ==============
// 2048 blocks = 32 dgroups(128 d) x 64 rowgroups(64 rows). 8 blocks/CU.
__global__ __launch_bounds__(256, 8)
void kB(const float* __restrict__ in, const float* __restrict__ W,
        const float* __restrict__ Wstat, float* __restrict__ ws,
        float* __restrict__ ypart) {
    __shared__ __align__(16) float tile[64 * 33];     // 8.4 KB
    __shared__ __align__(16) float inv_s[128];
    int b = blockIdx.x, t = threadIdx.x;
    int dg = b & 31, rg = b >> 5;
    int dbase = dg * 128, rowbase = rg * 64;
    int chunk = t & 7, srow = t >> 3;                 // staging role (srow<32)
    int row = t & 63;
    int jq = __builtin_amdgcn_readfirstlane(t >> 6);  // wave-uniform -> s_load
    const float* inp = in + (size_t)(rowbase + srow) * DD + dbase + chunk * 4;
    float4 pf0 = *(const float4*)(inp);               // prefetch overlaps prologue
    float4 pf1 = *(const float4*)(inp + (size_t)32 * DD);
    {   // prologue: inv for this block's 128 cols from 16 KB L2-hot partials
        if (t < 128) {
            const float* part = ws + O_PART;
            float s = 0.f, q = 0.f;
            #pragma unroll
            for (int g = 0; g < 16; ++g) {
                s += part[(size_t)g * 8192 + dbase + t];
                q += part[(size_t)g * 8192 + 4096 + dbase + t];
            }
            float m = s * (1.0f / BB);
            float var = q * (1.0f / BB) - m * m; if (var < 0.f) var = 0.f;
            inv_s[t] = 1.0f / (sqrtf(var) + EPSF);
        }
        __syncthreads();
    }
    float acc[8];
    #pragma unroll
    for (int i = 0; i < 8; ++i) acc[i] = 0.f;
    const float* wbase = (jq < 2) ? (Wstat + jq * 8) : (W + (jq - 2) * 8);
    for (int stage = 0; stage < 4; ++stage) {
        int ds0 = stage * 32;
        float4 iv4 = *(const float4*)&inv_s[ds0 + chunk * 4];
        int b0 = srow * 33 + chunk * 4;               // scale folded into staging
        tile[b0 + 0] = pf0.x * iv4.x; tile[b0 + 1] = pf0.y * iv4.y;
        tile[b0 + 2] = pf0.z * iv4.z; tile[b0 + 3] = pf0.w * iv4.w;
        int b1 = (srow + 32) * 33 + chunk * 4;
        tile[b1 + 0] = pf1.x * iv4.x; tile[b1 + 1] = pf1.y * iv4.y;
        tile[b1 + 2] = pf1.z * iv4.z; tile[b1 + 3] = pf1.w * iv4.w;
        __syncthreads();
        if (stage < 3) {
            pf0 = *(const float4*)(inp + (stage + 1) * 32);
            pf1 = *(const float4*)(inp + (size_t)32 * DD + (stage + 1) * 32);
        }
        const float* trow = tile + row * 33;
        #pragma unroll 4
        for (int dl = 0; dl < 32; ++dl) {
            float xs = trow[dl];
            const float* wr = wbase + (size_t)(dbase + ds0 + dl) * 16;
            #pragma unroll
            for (int j = 0; j < 8; ++j) acc[j] += xs * wr[j];
        }
        __syncthreads();
    }
    float* dst = ypart + ((size_t)dg * BB + rowbase + row) * 32 + jq * 8;
    *(float4*)(dst + 0) = make_float4(acc[0], acc[1], acc[2], acc[3]);
    *(float4*)(dst + 4) = make_float4(acc[4], acc[5], acc[6], acc[7]);
}

// ============ kEF: reduce + gram + arrival barrier + solve + epilogue =======
// 64 blocks x 256. Basis p=0..15 -> Y[:,p], p=16 -> ones. True Gram from raw:
// G = Graw - SS^T/B; <P,1>=0. Ones-row of Wmat adjusted by shifts c = S/B.
__global__ __launch_bounds__(256, 2)
void kEF(float* __restrict__ ws, float* __restrict__ out) {
    __shared__ __align__(16) float yzs[64 * 36];      // 64 rows of raw [Ry|Rz|1]
    __shared__ float Sv[33], GA[17 * 17], gz[17 * 16], v[15][17], gad[15][16],
                     gzd[15][16], gu[17], u[17], st[2], wm[17 * 16];
    int b = blockIdx.x, t = threadIdx.x;
    int rowbase = b * 64;
    const float invB = 1.0f / BB;
    // phase 1: reduce ypart -> this block's 64 rows in LDS (no global yz)
    {
        const float* yp = ws + O_YPART;
        int r0 = t >> 5, c = t & 31;
        for (int sweep = 0; sweep < 8; ++sweep) {
            int r = sweep * 8 + r0;
            size_t off = (size_t)(rowbase + r) * 32 + c;
            float s = 0.f;
            #pragma unroll
            for (int dg = 0; dg < 32; ++dg) s += yp[(size_t)dg * (BB * 32) + off];
            yzs[r * 36 + c] = s;
            if (c == 0) yzs[r * 36 + 32] = 1.0f;
        }
    }
    __syncthreads();
    // phase 2: gram contribution (8-way split copies, device-scope atomics)
    {
        float* gm = ws + O_GRAMM + (size_t)(b & 7) * 1120;
        for (int p = t; p < 561; p += 256) {          // upper-tri pairs i<=j<=32
            int i = 0, rem = p;
            while (rem >= 33 - i) { rem -= 33 - i; ++i; }
            int j = i + rem;
            float a2 = 0.f;
            for (int r = 0; r < 64; ++r) a2 += yzs[r * 36 + i] * yzs[r * 36 + j];
            atomicAdd(&gm[i * 33 + j], a2);
        }
    }
    __syncthreads();
    // phase 3: arrival barrier (64 blocks always co-resident on 256 CUs)
    {
        unsigned int* cnt = (unsigned int*)(ws + O_CNT);
        if (t == 0) {
            __threadfence();                           // release gram atomics
            atomicAdd(cnt, 1u);
            while (__hip_atomic_load(cnt, __ATOMIC_ACQUIRE,
                                     __HIP_MEMORY_SCOPE_AGENT) < 64u) {}
        }
        __syncthreads();
    }
    // phase 4: centered Gram -> solve (agent-scope loads: XCD L2 coherence)
    const float* gm = ws + O_GRAMM;
    if (t < 33) {                                     // S_i = <R_i, 1>
        float s = 0.f;
        #pragma unroll
        for (int m = 0; m < 8; ++m) s += gload(&gm[m * 1120 + gidx(t, 32)]);
        Sv[t] = s;
    }
    __syncthreads();
    for (int idx = t; idx < 17 * 17; idx += 256) {    // centered GA
        int p = idx / 17, q = idx % 17;
        float val;
        if (p < 16 && q < 16) {
            float raw = 0.f;
            #pragma unroll
            for (int m = 0; m < 8; ++m) raw += gload(&gm[m * 1120 + gidx(p, q)]);
            val = raw - Sv[p] * Sv[q] * invB;
        } else if (p == 16 && q == 16) val = (float)BB;
        else val = 0.f;                               // <P,1> = 0 exactly
        GA[idx] = val;
    }
    for (int idx = t; idx < 17 * 16; idx += 256) {    // centered gz
        int p = idx / 16, tt = idx % 16;
        float val = 0.f;
        if (p < 16) {
            float raw = 0.f;
            #pragma unroll
            for (int m = 0; m < 8; ++m) raw += gload(&gm[m * 1120 + gidx(p, 16 + tt)]);
            val = raw - Sv[p] * Sv[16 + tt] * invB;
        }
        gz[idx] = val;
    }
    if (t < 17) u[t] = (t == 0) ? 1.f : 0.f;
    __syncthreads();
    for (int i = 0; i < 15; ++i) {
        if (t < 17) {                                 // gu = GA @ u
            float s = 0.f;
            for (int q = 0; q < 17; ++q) s += GA[t * 17 + q] * u[q];
            gu[t] = s;
        }
        __syncthreads();
        if (t == 0) {                                 // stats of c_i
            float mean = gu[16] * invB, e2 = 0.f;
            for (int p = 0; p < 17; ++p) e2 += u[p] * gu[p];
            e2 *= invB;
            float var = e2 - mean * mean; if (var < 0.f) var = 0.f;
            st[0] = mean; st[1] = 1.0f / (sqrtf(var) + EPSF);
        }
        __syncthreads();
        if (t < 17) v[i][t] = (u[t] - (t == 16 ? st[0] : 0.f)) * st[1];
        __syncthreads();
        if (t < 16) {                                 // conv_i . Y[:,k]
            float s = 0.f;
            for (int p = 0; p < 17; ++p) s += v[i][p] * GA[p * 17 + t];
            gad[i][t] = s;
        } else if (t < 32) {                          // conv_i . Z[:,tt]
            int tt = t - 16;
            float s = 0.f;
            for (int p = 0; p < 17; ++p) s += v[i][p] * gz[p * 16 + tt];
            gzd[i][tt] = s;
        }
        __syncthreads();
        if (t < 17) {                                 // u_{i+1}
            float a2 = 0.f;
            for (int j = 0; j <= i; ++j) a2 += v[j][t] * gad[j][i + 1];
            u[t] = ((t == i + 1) ? 1.f : 0.f) - a2 * invB;
        }
        __syncthreads();
    }
    for (int idx = t; idx < 17 * 16; idx += 256) {
        int p = idx / 16, tt = idx % 16;
        float s = 0.f;
        for (int j = 0; j < tt; ++j) s += v[j][p] * gzd[j][tt];
        wm[idx] = s * invB;
    }
    __syncthreads();
    if (t < 16) {                                     // fold shifts into ones-row
        float adj = Sv[16 + t] * invB;
        for (int p = 0; p < 16; ++p) adj -= Sv[p] * invB * wm[p * 16 + t];
        wm[16 * 16 + t] += adj;
    }
    __syncthreads();
    // epilogue on raw R (already in LDS): 4 outputs/thread, float4 store
    int row = t >> 2, c0 = (t & 3) * 4;
    const float* yr = yzs + row * 36;
    float o[4];
    #pragma unroll
    for (int k = 0; k < 4; ++k) o[k] = yr[16 + c0 + k] - wm[16 * 16 + c0 + k];
    #pragma unroll
    for (int p = 0; p < 16; ++p) {
        float yp = yr[p];
        #pragma unroll
        for (int k = 0; k < 4; ++k) o[k] -= yp * wm[p * 16 + c0 + k];
    }
    *(float4*)&out[(size_t)rowbase * 16 + t * 4] = make_float4(o[0], o[1], o[2], o[3]);
}

extern "C" void kernel_launch(void* const* d_in, const int* in_sizes, int n_in,
                              void* d_out, int out_size, void* d_ws, size_t ws_size,
                              hipStream_t stream) {
    const float* in    = (const float*)d_in[0];
    const float* W     = (const float*)d_in[1];
    const float* Wstat = (const float*)d_in[2];
    float* ws  = (float*)d_ws;
    float* out = (float*)d_out;

    kA<<<dim3(512),  dim3(256), 0, stream>>>(in, ws);
    kB<<<dim3(2048), dim3(256), 0, stream>>>(in, W, Wstat, ws, ws + O_YPART);
    kEF<<<dim3(64),  dim3(256), 0, stream>>>(ws, out);
}

// Round 13
// 152.516 us; speedup vs baseline: 1.0019x; 1.0019x over previous
//
#include <hip/hip_runtime.h>
#include <stdint.h>

// FactorLayer: B=4096, D=4096, T=16, float32.
// X = znorm(inputs); Y = X@W_static; Z = X@W; sequential deflation collapses
// to 17-dim recurrences on the Gram of [Y|Z|1]; Out = Z - [Y|1]@Wmat.
// Structure (R13): 3 launches. kA: stats partials + zero gram/counter.
// kB: pure GEMM R = (in.diag(inv)) @ [Wstat|W], raw weights s_load'ed via
// wave-uniform jq. kEF: per-block yz reduce (LDS) + gram atomics + device
// arrival barrier + centered-Gram solve + epilogue.
// R12 lesson: a TIGHT spin on one cacheline convoys the L2 atomic unit
// (63 spinners starve the arriving atomicAdd; kEF 42us under rocprof).
// R13: s_sleep(8) backoff in the poll loop (~0.2us/poll) -- line pressure
// drops 1000x, adds service immediately, exit within one quantum.
// Journal: R3 coop launch no-ops. R7: weight ptr off raw t>>7 kills s_load
// (use readfirstlane). Fixed harness cost ~105-110us; kernel floor ~26us.

#define BB 4096
#define DD 4096
#define EPSF 1e-6f

// ws layout (float indices)
#define O_PART    0u          // [16 rowgroups][8192]: colsum(0..4095), colsq(4096..8191)
#define O_GRAMM   131072u     // 8 copies x 1120 (33x33, upper-tri used)
#define O_CNT     140032u     // arrival counter (1 word, zeroed by kA)
#define O_YPART   271360u     // [32 dgroups][4096][32] (16B-aligned)

__device__ __forceinline__ int gidx(int a, int b) {   // upper-tri gram index
    int lo = a < b ? a : b, hi = a < b ? b : a;
    return lo * 33 + hi;
}
__device__ __forceinline__ float gload(const float* p) {  // agent-scope load
    return __hip_atomic_load(p, __ATOMIC_RELAXED, __HIP_MEMORY_SCOPE_AGENT);
}

// ============ kA: stats partials (16 rowgroups) + zero gram/counter =========
// 512 blocks = 32 colgroups(128 cols) x 16 rowgroups(256 rows).
__global__ __launch_bounds__(256, 2)
void kA(const float* __restrict__ in, float* __restrict__ ws) {
    __shared__ float rs[8 * 132], rq[8 * 132];        // pad 132: no 8-way bank hits
    int b = blockIdx.x, t = threadIdx.x;
    int idx = b * 256 + t;
    if (idx < 8961) ws[O_GRAMM + idx] = 0.f;          // 8 gram copies + counter
    int cg = b & 31, rg = b >> 5;
    int dbase = cg * 128, r0 = rg * 256;
    int chunk = t & 31, rr = t >> 5;
    int c0 = dbase + chunk * 4;
    float s0=0.f,s1=0.f,s2=0.f,s3=0.f,q0=0.f,q1=0.f,q2=0.f,q3=0.f;
    #pragma unroll 4
    for (int i = 0; i < 32; ++i) {
        int r = r0 + i * 8 + rr;
        float4 u = *(const float4*)&in[(size_t)r * DD + c0];
        s0 += u.x; q0 += u.x*u.x;  s1 += u.y; q1 += u.y*u.y;
        s2 += u.z; q2 += u.z*u.z;  s3 += u.w; q3 += u.w*u.w;
    }
    int lb = rr * 132 + chunk * 4;
    rs[lb+0]=s0; rs[lb+1]=s1; rs[lb+2]=s2; rs[lb+3]=s3;
    rq[lb+0]=q0; rq[lb+1]=q1; rq[lb+2]=q2; rq[lb+3]=q3;
    __syncthreads();
    float* part = ws + O_PART + (size_t)rg * 8192;
    if (t < 128) {
        float a = 0.f;
        #pragma unroll
        for (int r2 = 0; r2 < 8; ++r2) a += rs[r2 * 132 + t];
        part[dbase + t] = a;
    } else {
        int ci = t - 128;
        float a = 0.f;
        #pragma unroll
        for (int r2 = 0; r2 < 8; ++r2) a += rq[r2 * 132 + ci];
        part[4096 + dbase + ci] = a;
    }
}

// ============ kB: inv-prologue + pure GEMM R = (in.inv) @ Wcat ==============
// 2048 blocks = 32 dgroups(128 d) x 64 rowgroups(64 rows). 8 blocks/CU.
__global__ __launch_bounds__(256, 8)
void kB(const float* __restrict__ in, const float* __restrict__ W,
        const float* __restrict__ Wstat, float* __restrict__ ws,
        float* __restrict__ ypart) {
    __shared__ __align__(16) float tile[64 * 33];     // 8.4 KB
    __shared__ __align__(16) float inv_s[128];
    int b = blockIdx.x, t = threadIdx.x;
    int dg = b & 31, rg = b >> 5;
    int dbase = dg * 128, rowbase = rg * 64;
    int chunk = t & 7, srow = t >> 3;                 // staging role (srow<32)
    int row = t & 63;
    int jq = __builtin_amdgcn_readfirstlane(t >> 6);  // wave-uniform -> s_load
    const float* inp = in + (size_t)(rowbase + srow) * DD + dbase + chunk * 4;
    float4 pf0 = *(const float4*)(inp);               // prefetch overlaps prologue
    float4 pf1 = *(const float4*)(inp + (size_t)32 * DD);
    {   // prologue: inv for this block's 128 cols from 16 KB L2-hot partials
        if (t < 128) {
            const float* part = ws + O_PART;
            float s = 0.f, q = 0.f;
            #pragma unroll
            for (int g = 0; g < 16; ++g) {
                s += part[(size_t)g * 8192 + dbase + t];
                q += part[(size_t)g * 8192 + 4096 + dbase + t];
            }
            float m = s * (1.0f / BB);
            float var = q * (1.0f / BB) - m * m; if (var < 0.f) var = 0.f;
            inv_s[t] = 1.0f / (sqrtf(var) + EPSF);
        }
        __syncthreads();
    }
    float acc[8];
    #pragma unroll
    for (int i = 0; i < 8; ++i) acc[i] = 0.f;
    const float* wbase = (jq < 2) ? (Wstat + jq * 8) : (W + (jq - 2) * 8);
    for (int stage = 0; stage < 4; ++stage) {
        int ds0 = stage * 32;
        float4 iv4 = *(const float4*)&inv_s[ds0 + chunk * 4];
        int b0 = srow * 33 + chunk * 4;               // scale folded into staging
        tile[b0 + 0] = pf0.x * iv4.x; tile[b0 + 1] = pf0.y * iv4.y;
        tile[b0 + 2] = pf0.z * iv4.z; tile[b0 + 3] = pf0.w * iv4.w;
        int b1 = (srow + 32) * 33 + chunk * 4;
        tile[b1 + 0] = pf1.x * iv4.x; tile[b1 + 1] = pf1.y * iv4.y;
        tile[b1 + 2] = pf1.z * iv4.z; tile[b1 + 3] = pf1.w * iv4.w;
        __syncthreads();
        if (stage < 3) {
            pf0 = *(const float4*)(inp + (stage + 1) * 32);
            pf1 = *(const float4*)(inp + (size_t)32 * DD + (stage + 1) * 32);
        }
        const float* trow = tile + row * 33;
        #pragma unroll 4
        for (int dl = 0; dl < 32; ++dl) {
            float xs = trow[dl];
            const float* wr = wbase + (size_t)(dbase + ds0 + dl) * 16;
            #pragma unroll
            for (int j = 0; j < 8; ++j) acc[j] += xs * wr[j];
        }
        __syncthreads();
    }
    float* dst = ypart + ((size_t)dg * BB + rowbase + row) * 32 + jq * 8;
    *(float4*)(dst + 0) = make_float4(acc[0], acc[1], acc[2], acc[3]);
    *(float4*)(dst + 4) = make_float4(acc[4], acc[5], acc[6], acc[7]);
}

// ============ kEF: reduce + gram + arrival barrier + solve + epilogue =======
// 64 blocks x 256. Basis p=0..15 -> Y[:,p], p=16 -> ones. True Gram from raw:
// G = Graw - SS^T/B; <P,1>=0. Ones-row of Wmat adjusted by shifts c = S/B.
__global__ __launch_bounds__(256, 2)
void kEF(float* __restrict__ ws, float* __restrict__ out) {
    __shared__ __align__(16) float yzs[64 * 36];      // 64 rows of raw [Ry|Rz|1]
    __shared__ float Sv[33], GA[17 * 17], gz[17 * 16], v[15][17], gad[15][16],
                     gzd[15][16], gu[17], u[17], st[2], wm[17 * 16];
    int b = blockIdx.x, t = threadIdx.x;
    int rowbase = b * 64;
    const float invB = 1.0f / BB;
    // phase 1: reduce ypart -> this block's 64 rows in LDS (no global yz)
    {
        const float* yp = ws + O_YPART;
        int r0 = t >> 5, c = t & 31;
        for (int sweep = 0; sweep < 8; ++sweep) {
            int r = sweep * 8 + r0;
            size_t off = (size_t)(rowbase + r) * 32 + c;
            float s = 0.f;
            #pragma unroll
            for (int dg = 0; dg < 32; ++dg) s += yp[(size_t)dg * (BB * 32) + off];
            yzs[r * 36 + c] = s;
            if (c == 0) yzs[r * 36 + 32] = 1.0f;
        }
    }
    __syncthreads();
    // phase 2: gram contribution (8-way split copies, device-scope atomics)
    {
        float* gm = ws + O_GRAMM + (size_t)(b & 7) * 1120;
        for (int p = t; p < 561; p += 256) {          // upper-tri pairs i<=j<=32
            int i = 0, rem = p;
            while (rem >= 33 - i) { rem -= 33 - i; ++i; }
            int j = i + rem;
            float a2 = 0.f;
            for (int r = 0; r < 64; ++r) a2 += yzs[r * 36 + i] * yzs[r * 36 + j];
            atomicAdd(&gm[i * 33 + j], a2);
        }
    }
    __syncthreads();
    // phase 3: arrival barrier with SLEEP BACKOFF (R12: tight spin convoyed
    // the L2 atomic unit -- 63 spinners starved the arriving atomicAdd).
    {
        unsigned int* cnt = (unsigned int*)(ws + O_CNT);
        if (t == 0) {
            __threadfence();                           // release gram atomics
            atomicAdd(cnt, 1u);
            while (__hip_atomic_load(cnt, __ATOMIC_ACQUIRE,
                                     __HIP_MEMORY_SCOPE_AGENT) < 64u) {
                __builtin_amdgcn_s_sleep(8);           // ~512 cyc between polls
            }
        }
        __syncthreads();
    }
    // phase 4: centered Gram -> solve (agent-scope loads: XCD L2 coherence)
    const float* gm = ws + O_GRAMM;
    if (t < 33) {                                     // S_i = <R_i, 1>
        float s = 0.f;
        #pragma unroll
        for (int m = 0; m < 8; ++m) s += gload(&gm[m * 1120 + gidx(t, 32)]);
        Sv[t] = s;
    }
    __syncthreads();
    for (int idx = t; idx < 17 * 17; idx += 256) {    // centered GA
        int p = idx / 17, q = idx % 17;
        float val;
        if (p < 16 && q < 16) {
            float raw = 0.f;
            #pragma unroll
            for (int m = 0; m < 8; ++m) raw += gload(&gm[m * 1120 + gidx(p, q)]);
            val = raw - Sv[p] * Sv[q] * invB;
        } else if (p == 16 && q == 16) val = (float)BB;
        else val = 0.f;                               // <P,1> = 0 exactly
        GA[idx] = val;
    }
    for (int idx = t; idx < 17 * 16; idx += 256) {    // centered gz
        int p = idx / 16, tt = idx % 16;
        float val = 0.f;
        if (p < 16) {
            float raw = 0.f;
            #pragma unroll
            for (int m = 0; m < 8; ++m) raw += gload(&gm[m * 1120 + gidx(p, 16 + tt)]);
            val = raw - Sv[p] * Sv[16 + tt] * invB;
        }
        gz[idx] = val;
    }
    if (t < 17) u[t] = (t == 0) ? 1.f : 0.f;
    __syncthreads();
    for (int i = 0; i < 15; ++i) {
        if (t < 17) {                                 // gu = GA @ u
            float s = 0.f;
            for (int q = 0; q < 17; ++q) s += GA[t * 17 + q] * u[q];
            gu[t] = s;
        }
        __syncthreads();
        if (t == 0) {                                 // stats of c_i
            float mean = gu[16] * invB, e2 = 0.f;
            for (int p = 0; p < 17; ++p) e2 += u[p] * gu[p];
            e2 *= invB;
            float var = e2 - mean * mean; if (var < 0.f) var = 0.f;
            st[0] = mean; st[1] = 1.0f / (sqrtf(var) + EPSF);
        }
        __syncthreads();
        if (t < 17) v[i][t] = (u[t] - (t == 16 ? st[0] : 0.f)) * st[1];
        __syncthreads();
        if (t < 16) {                                 // conv_i . Y[:,k]
            float s = 0.f;
            for (int p = 0; p < 17; ++p) s += v[i][p] * GA[p * 17 + t];
            gad[i][t] = s;
        } else if (t < 32) {                          // conv_i . Z[:,tt]
            int tt = t - 16;
            float s = 0.f;
            for (int p = 0; p < 17; ++p) s += v[i][p] * gz[p * 16 + tt];
            gzd[i][tt] = s;
        }
        __syncthreads();
        if (t < 17) {                                 // u_{i+1}
            float a2 = 0.f;
            for (int j = 0; j <= i; ++j) a2 += v[j][t] * gad[j][i + 1];
            u[t] = ((t == i + 1) ? 1.f : 0.f) - a2 * invB;
        }
        __syncthreads();
    }
    for (int idx = t; idx < 17 * 16; idx += 256) {
        int p = idx / 16, tt = idx % 16;
        float s = 0.f;
        for (int j = 0; j < tt; ++j) s += v[j][p] * gzd[j][tt];
        wm[idx] = s * invB;
    }
    __syncthreads();
    if (t < 16) {                                     // fold shifts into ones-row
        float adj = Sv[16 + t] * invB;
        for (int p = 0; p < 16; ++p) adj -= Sv[p] * invB * wm[p * 16 + t];
        wm[16 * 16 + t] += adj;
    }
    __syncthreads();
    // epilogue on raw R (already in LDS): 4 outputs/thread, float4 store
    int row = t >> 2, c0 = (t & 3) * 4;
    const float* yr = yzs + row * 36;
    float o[4];
    #pragma unroll
    for (int k = 0; k < 4; ++k) o[k] = yr[16 + c0 + k] - wm[16 * 16 + c0 + k];
    #pragma unroll
    for (int p = 0; p < 16; ++p) {
        float yp = yr[p];
        #pragma unroll
        for (int k = 0; k < 4; ++k) o[k] -= yp * wm[p * 16 + c0 + k];
    }
    *(float4*)&out[(size_t)rowbase * 16 + t * 4] = make_float4(o[0], o[1], o[2], o[3]);
}

extern "C" void kernel_launch(void* const* d_in, const int* in_sizes, int n_in,
                              void* d_out, int out_size, void* d_ws, size_t ws_size,
                              hipStream_t stream) {
    const float* in    = (const float*)d_in[0];
    const float* W     = (const float*)d_in[1];
    const float* Wstat = (const float*)d_in[2];
    float* ws  = (float*)d_ws;
    float* out = (float*)d_out;

    kA<<<dim3(512),  dim3(256), 0, stream>>>(in, ws);
    kB<<<dim3(2048), dim3(256), 0, stream>>>(in, W, Wstat, ws, ws + O_YPART);
    kEF<<<dim3(64),  dim3(256), 0, stream>>>(ws, out);
}